// Round 6
// baseline (255.162 us; speedup 1.0000x reference)
//
#include <hip/hip_runtime.h>
#include <math.h>

// Problem constants
#define QN 4096
#define MN 65536
#define DN 384
#define CN 128
#define NCHUNK 64                 // m-chunks
#define MROWS_PER_CHUNK (MN / NCHUNK)   // 1024
#define MT_PER (MROWS_PER_CHUNK / 64)   // 16 m-tiles (64 rows) per block
#define BTILE_B (64 * DN)               // 24576 B per B tile
#define NBUF 3                          // triple-buffer

typedef __attribute__((ext_vector_type(8))) int i32x8;
typedef __attribute__((ext_vector_type(4))) int i32x4;
typedef __attribute__((ext_vector_type(4))) float f32x4;

// f32 -> OCP e4m3fn
__device__ __forceinline__ unsigned char f2fp8(float f) {
  return (unsigned char)(__builtin_amdgcn_cvt_pk_fp8_f32(f, 0.f, 0, false) & 0xff);
}

__device__ __forceinline__ void async16(const void* g, void* l) {
  __builtin_amdgcn_global_load_lds(
      (const __attribute__((address_space(1))) unsigned int*)g,
      (__attribute__((address_space(3))) unsigned int*)l, 16, 0, 0);
}

// ------- Kernel A: L2-normalize rows (q then m) -> fp8, one wave per row ---
__global__ __launch_bounds__(256) void nrm_kernel(const float* __restrict__ qe,
                                                  const float* __restrict__ me,
                                                  unsigned char* __restrict__ yq,
                                                  unsigned char* __restrict__ ym) {
  const int row = blockIdx.x * 4 + (threadIdx.x >> 6);
  const int lane = threadIdx.x & 63;
  const float* xr;
  unsigned char* yr;
  if (row < QN) {
    xr = qe + (size_t)row * DN;
    yr = yq + (size_t)row * DN;
  } else {
    xr = me + (size_t)(row - QN) * DN;
    yr = ym + (size_t)(row - QN) * DN;
  }
  float v[6];
  float ss = 0.f;
#pragma unroll
  for (int i = 0; i < 6; ++i) {
    v[i] = xr[lane + i * 64];
    ss += v[i] * v[i];
  }
#pragma unroll
  for (int m = 1; m < 64; m <<= 1) ss += __shfl_xor(ss, m);
  const float scale = 1.0f / fmaxf(sqrtf(ss), 1e-8f);
#pragma unroll
  for (int i = 0; i < 6; ++i) yr[lane + i * 64] = f2fp8(v[i] * scale);
}

// ------- Kernel B: MX-fp8 GEMM, loop-carried kc0 prefetch ------------------
// R6: R5 counters prove strict phase serialization: per-visit 1650 cyc ==
// MFMA 830 (MfmaUtil 50%) + LDS 800, because at barrier-exit NO wave has a
// ready MFMA — every MFMA of tile t waits on tile t's post-barrier ds_reads.
// Fix: loop-carry tile t's kc0 fragments in registers (bfr0, +16 VGPR only —
// R4's +48 spilled). Region 1: kc0+kc1 MFMAs (kc0 ready at barrier-exit)
// overlap kc1/kc2 ds_reads. Mid-body vmcnt+barrier publishes tile t+1's
// staging; region 2: prefetch t+1's kc0 into bfr0 under the kc2 MFMAs.
// 3 buffers: t+1's kc0 read targets buf (t+1)%3, restaged at iter t+2 only.
__global__ __launch_bounds__(256, 2) void gemm_max_kernel(
    const unsigned char* __restrict__ qn8, const unsigned char* __restrict__ mn8,
    float* __restrict__ pmax) {
  __shared__ unsigned char Bs[NBUF * BTILE_B];  // 72 KB (A staged here first)
  __shared__ float smax[2][128];

  const int tid = threadIdx.x;
  const int wave = tid >> 6, lane = tid & 63;
  const int wr = wave >> 1, wc = wave & 1;   // waves: 2x2 over 128q x 64m
  const int quad = lane >> 4, l16 = lane & 15;
  const int r7 = l16 & 7;

  // --- XCD-partitioned bijective swizzle (HW assigns XCD = linear id % 8) ---
  const int bid = blockIdx.y * gridDim.x + blockIdx.x;  // linear dispatch id
  const int xcd = bid & 7;
  const int j = bid >> 3;                    // 0..255 within this XCD
  const int ychunk = (xcd << 3) | (j >> 5);  // 8 m-chunks per XCD
  const int qrow0 = (j & 31) * 128;          // x sweeps fastest
  const int mchunk0 = ychunk * MROWS_PER_CHUNK;

  float rmax[16];
#pragma unroll
  for (int i = 0; i < 16; ++i) rmax[i] = -3.0e38f;

  // ---- stage A tile (128x384 = 48 KB) once, hoist fragments to registers --
  {
    const unsigned char* abase = qn8 + (size_t)qrow0 * DN;
#pragma unroll
    for (int i = 0; i < 12; ++i) {
      const int ci = i * 256 + tid;               // 16B chunk 0..3071
      const int row = ci / 24;
      const int jj = ci - row * 24;
      const int gj = (jj & 24) | ((jj ^ row) & 7);  // XOR-swizzled source chunk
      async16(abase + row * DN + gj * 16, &Bs[(i * 256 + wave * 64) * 16]);
    }
  }
  __syncthreads();  // full drain: A staged
  i32x8 afr[3][4];
#pragma unroll
  for (int kc = 0; kc < 3; ++kc)
#pragma unroll
    for (int rt = 0; rt < 4; ++rt) {
      const unsigned char* p = &Bs[(wr * 64 + rt * 16 + l16) * DN];
      i32x4 lo = *(const i32x4*)&p[(kc * 8 + ((quad * 2 + 0) ^ r7)) * 16];
      i32x4 hi = *(const i32x4*)&p[(kc * 8 + ((quad * 2 + 1) ^ r7)) * 16];
      afr[kc][rt][0] = lo[0]; afr[kc][rt][1] = lo[1];
      afr[kc][rt][2] = lo[2]; afr[kc][rt][3] = lo[3];
      afr[kc][rt][4] = hi[0]; afr[kc][rt][5] = hi[1];
      afr[kc][rt][6] = hi[2]; afr[kc][rt][7] = hi[3];
    }
  __syncthreads();  // afr reads done; LDS free for B staging

  // B staging source offsets: 6 issues/thread per 64-row tile (1536 chunks)
  int srcoff[6];
#pragma unroll
  for (int i = 0; i < 6; ++i) {
    const int ci = i * 256 + tid;                 // 16B chunk 0..1535
    const int row = ci / 24;
    const int jj = ci - row * 24;
    const int gj = (jj & 24) | ((jj ^ row) & 7);
    srcoff[i] = row * DN + gj * 16;
  }

  const unsigned char* bchunk = mn8 + (size_t)mchunk0 * DN;
  // prologue: stage tile 0 -> buf 0, tile 1 -> buf 1 (12 loads in flight)
#pragma unroll
  for (int t = 0; t < 2; ++t)
#pragma unroll
    for (int i = 0; i < 6; ++i)
      async16(bchunk + (size_t)t * BTILE_B + srcoff[i],
              &Bs[t * BTILE_B + (i * 256 + wave * 64) * 16]);

  asm volatile("s_waitcnt vmcnt(6)" ::: "memory");  // tile 0 landed (mine)
  __builtin_amdgcn_s_barrier();                     // ... for everyone
  __builtin_amdgcn_sched_barrier(0);

  // loop-carried kc0 fragments (tile 0)
  i32x8 bfr0[2];
#pragma unroll
  for (int ct = 0; ct < 2; ++ct) {
    const unsigned char* p = &Bs[(wc * 32 + ct * 16 + l16) * DN];
    i32x4 lo = *(const i32x4*)&p[(((quad * 2 + 0) ^ r7)) * 16];
    i32x4 hi = *(const i32x4*)&p[(((quad * 2 + 1) ^ r7)) * 16];
    bfr0[ct][0] = lo[0]; bfr0[ct][1] = lo[1];
    bfr0[ct][2] = lo[2]; bfr0[ct][3] = lo[3];
    bfr0[ct][4] = hi[0]; bfr0[ct][5] = hi[1];
    bfr0[ct][6] = hi[2]; bfr0[ct][7] = hi[3];
  }

  int cb = 0;                    // buffer holding tile mt
  int sb = 2;                    // buffer to stage tile mt+2 into

#pragma unroll 1
  for (int mt = 0; mt < MT_PER; ++mt) {
    __builtin_amdgcn_s_barrier();       // tile mt landed for all (prev iter's
                                        // publish); tile mt-1 reads all done
    __builtin_amdgcn_sched_barrier(0);

    const unsigned char* cur = &Bs[cb * BTILE_B];

    // region 1: read kc1,kc2 fragments; stage tile mt+2; MFMA kc0 (ready!)
    // and kc1 — compiler interleaves partial lgkm waits.
    i32x8 bfr12[2][2];
#pragma unroll
    for (int k2 = 0; k2 < 2; ++k2)
#pragma unroll
      for (int ct = 0; ct < 2; ++ct) {
        const int kc = k2 + 1;
        const unsigned char* p = &cur[(wc * 32 + ct * 16 + l16) * DN];
        i32x4 lo = *(const i32x4*)&p[(kc * 8 + ((quad * 2 + 0) ^ r7)) * 16];
        i32x4 hi = *(const i32x4*)&p[(kc * 8 + ((quad * 2 + 1) ^ r7)) * 16];
        bfr12[k2][ct][0] = lo[0]; bfr12[k2][ct][1] = lo[1];
        bfr12[k2][ct][2] = lo[2]; bfr12[k2][ct][3] = lo[3];
        bfr12[k2][ct][4] = hi[0]; bfr12[k2][ct][5] = hi[1];
        bfr12[k2][ct][6] = hi[2]; bfr12[k2][ct][7] = hi[3];
      }

    if (mt + 2 < MT_PER) {
      unsigned char* dst = &Bs[sb * BTILE_B];
      const unsigned char* nb = bchunk + (size_t)(mt + 2) * BTILE_B;
#pragma unroll
      for (int i = 0; i < 6; ++i)
        async16(nb + srcoff[i], &dst[(i * 256 + wave * 64) * 16]);
    }

    f32x4 acc[4][2];
#pragma unroll
    for (int rt = 0; rt < 4; ++rt)
#pragma unroll
      for (int ct = 0; ct < 2; ++ct) acc[rt][ct] = (f32x4){0.f, 0.f, 0.f, 0.f};

    __builtin_amdgcn_s_setprio(1);
#pragma unroll
    for (int rt = 0; rt < 4; ++rt)
#pragma unroll
      for (int ct = 0; ct < 2; ++ct)
        acc[rt][ct] = __builtin_amdgcn_mfma_scale_f32_16x16x128_f8f6f4(
            afr[0][rt], bfr0[ct], acc[rt][ct], 0, 0, 0, 0x7f7f7f7f, 0,
            0x7f7f7f7f);
#pragma unroll
    for (int rt = 0; rt < 4; ++rt)
#pragma unroll
      for (int ct = 0; ct < 2; ++ct)
        acc[rt][ct] = __builtin_amdgcn_mfma_scale_f32_16x16x128_f8f6f4(
            afr[1][rt], bfr12[0][ct], acc[rt][ct], 0, 0, 0, 0x7f7f7f7f, 0,
            0x7f7f7f7f);
    __builtin_amdgcn_s_setprio(0);
    __builtin_amdgcn_sched_barrier(0);  // pin region-1 work above the publish

    // region 2: publish tile mt+1's staging; prefetch its kc0 into bfr0
    if (mt + 1 < MT_PER) {
      if (mt + 2 < MT_PER)
        asm volatile("s_waitcnt vmcnt(6)" ::: "memory");  // mt+1 landed (mine)
      else
        asm volatile("s_waitcnt vmcnt(0)" ::: "memory");  // tail: only mt+1 out
      __builtin_amdgcn_s_barrier();     // everyone's mt+1 staging visible
      __builtin_amdgcn_sched_barrier(0);
      const unsigned char* nxt = &Bs[((cb == 2) ? 0 : cb + 1) * BTILE_B];
#pragma unroll
      for (int ct = 0; ct < 2; ++ct) {
        const unsigned char* p = &nxt[(wc * 32 + ct * 16 + l16) * DN];
        i32x4 lo = *(const i32x4*)&p[(((quad * 2 + 0) ^ r7)) * 16];
        i32x4 hi = *(const i32x4*)&p[(((quad * 2 + 1) ^ r7)) * 16];
        bfr0[ct][0] = lo[0]; bfr0[ct][1] = lo[1];
        bfr0[ct][2] = lo[2]; bfr0[ct][3] = lo[3];
        bfr0[ct][4] = hi[0]; bfr0[ct][5] = hi[1];
        bfr0[ct][6] = hi[2]; bfr0[ct][7] = hi[3];
      }
    }

    __builtin_amdgcn_s_setprio(1);
#pragma unroll
    for (int rt = 0; rt < 4; ++rt)
#pragma unroll
      for (int ct = 0; ct < 2; ++ct)
        acc[rt][ct] = __builtin_amdgcn_mfma_scale_f32_16x16x128_f8f6f4(
            afr[2][rt], bfr12[1][ct], acc[rt][ct], 0, 0, 0, 0x7f7f7f7f, 0,
            0x7f7f7f7f);
    __builtin_amdgcn_s_setprio(0);

#pragma unroll
    for (int rt = 0; rt < 4; ++rt)
#pragma unroll
      for (int r = 0; r < 4; ++r) {
        const float v = fmaxf(acc[rt][0][r], acc[rt][1][r]);
        rmax[rt * 4 + r] = fmaxf(rmax[rt * 4 + r], v);
      }

    // rotate buffers: cb -> cb+1, sb -> sb+1 (mod 3)
    cb = (cb == 2) ? 0 : cb + 1;
    sb = (sb == 2) ? 0 : sb + 1;
  }

#pragma unroll
  for (int i = 0; i < 16; ++i) {
    float v = rmax[i];
    v = fmaxf(v, __shfl_xor(v, 1));
    v = fmaxf(v, __shfl_xor(v, 2));
    v = fmaxf(v, __shfl_xor(v, 4));
    v = fmaxf(v, __shfl_xor(v, 8));
    rmax[i] = v;
  }
  if (l16 == 0) {
#pragma unroll
    for (int rt = 0; rt < 4; ++rt)
#pragma unroll
      for (int r = 0; r < 4; ++r)
        smax[wc][wr * 64 + rt * 16 + quad * 4 + r] = rmax[rt * 4 + r];
  }
  __syncthreads();
  if (tid < 128) {
    const float v = fmaxf(smax[0][tid], smax[1][tid]);
    pmax[(size_t)(qrow0 + tid) * NCHUNK + ychunk] = v;
  }
}

// ------- Kernel C: reduce partials; uniform row OR exact fp32 re-check -----
__global__ __launch_bounds__(256) void decide_kernel(
    const float* __restrict__ pmax, const float* __restrict__ qe,
    const float* __restrict__ me, const float* __restrict__ labels,
    float* __restrict__ out) {
  const int q = blockIdx.x;
  const int t = threadIdx.x;  // 256
  __shared__ float smx;
  if (t < 64) {
    float v = pmax[(size_t)q * NCHUNK + t];  // NCHUNK == 64
#pragma unroll
    for (int m = 1; m < 64; m <<= 1) v = fmaxf(v, __shfl_xor(v, m));
    if (t == 0) smx = v;
  }
  __syncthreads();
  if (smx <= 0.5f) {  // uniform fast path (expected for all queries)
    if (t < CN) out[(size_t)q * CN + t] = 1.0f / 128.0f;
    return;
  }
  // exact fp32 path (rare / borderline queries only)
  __shared__ float sred[256];
  __shared__ int sidx[256];
  __shared__ float wsum[4];
  const float* qr = qe + (size_t)q * DN;
  float ss = 0.f;
  for (int i = t; i < DN; i += 256) ss += qr[i] * qr[i];
#pragma unroll
  for (int m = 1; m < 64; m <<= 1) ss += __shfl_xor(ss, m);
  if ((t & 63) == 0) wsum[t >> 6] = ss;
  __syncthreads();
  const float qnorm = fmaxf(sqrtf(wsum[0] + wsum[1] + wsum[2] + wsum[3]), 1e-8f);

  float best = -3.0e38f;
  int bidx = 0x7fffffff;
  for (int j = t; j < MN; j += 256) {
    const float* mr = me + (size_t)j * DN;
    float dot = 0.f, ms = 0.f;
    for (int k = 0; k < DN; ++k) {
      float a = qr[k], b = mr[k];
      dot += a * b;
      ms += b * b;
    }
    const float sim = dot / (qnorm * fmaxf(sqrtf(ms), 1e-8f));
    if (sim > best) { best = sim; bidx = j; }  // strict > keeps first index
  }
  sred[t] = best;
  sidx[t] = bidx;
  __syncthreads();
  for (int s = 128; s > 0; s >>= 1) {
    if (t < s) {
      const float ov = sred[t + s];
      const int oi = sidx[t + s];
      if (ov > sred[t] || (ov == sred[t] && oi < sidx[t])) {
        sred[t] = ov;
        sidx[t] = oi;
      }
    }
    __syncthreads();
  }
  const float mx = sred[0];
  const int mi = sidx[0];
  if (t < CN)
    out[(size_t)q * CN + t] =
        (mx > 0.7f) ? labels[(size_t)mi * CN + t] : (1.0f / 128.0f);
}

extern "C" void kernel_launch(void* const* d_in, const int* in_sizes, int n_in,
                              void* d_out, int out_size, void* d_ws,
                              size_t ws_size, hipStream_t stream) {
  const float* qe = (const float*)d_in[0];  // [4096,384] f32
  const float* me = (const float*)d_in[1];  // [65536,384] f32
  const float* lb = (const float*)d_in[2];  // [65536,128] f32
  float* out = (float*)d_out;               // [4096,128] f32

  char* ws = (char*)d_ws;
  const size_t OFF_QN = 0;
  const size_t OFF_MN = OFF_QN + (size_t)QN * DN;        // 1,572,864
  const size_t OFF_PMAX = OFF_MN + (size_t)MN * DN;      // +25,165,824
  unsigned char* qn8 = (unsigned char*)(ws + OFF_QN);
  unsigned char* mn8 = (unsigned char*)(ws + OFF_MN);
  float* pmax = (float*)(ws + OFF_PMAX);                 // [4096][64] = 1 MB

  nrm_kernel<<<(QN + MN) / 4, 256, 0, stream>>>(qe, me, qn8, mn8);
  gemm_max_kernel<<<dim3(QN / 128, NCHUNK), 256, 0, stream>>>(qn8, mn8, pmax);
  decide_kernel<<<QN, 256, 0, stream>>>(pmax, qe, me, lb, out);
}

// Round 7
// 246.569 us; speedup vs baseline: 1.0349x; 1.0349x over previous
//
#include <hip/hip_runtime.h>
#include <math.h>

// Problem constants
#define QN 4096
#define MN 65536
#define DN 384
#define CN 128
#define NCHUNK 64                 // m-chunks
#define MROWS_PER_CHUNK (MN / NCHUNK)   // 1024
#define MT_PER (MROWS_PER_CHUNK / 64)   // 16 m-tiles (64 rows) per block
#define BTILE_B (64 * DN)               // 24576 B per B tile
#define NBUF 3                          // triple-buffer: 1 barrier/tile

typedef __attribute__((ext_vector_type(8))) int i32x8;
typedef __attribute__((ext_vector_type(4))) int i32x4;
typedef __attribute__((ext_vector_type(4))) float f32x4;

__device__ __forceinline__ void async16(const void* g, void* l) {
  __builtin_amdgcn_global_load_lds(
      (const __attribute__((address_space(1))) unsigned int*)g,
      (__attribute__((address_space(3))) unsigned int*)l, 16, 0, 0);
}

// ------- Kernel A: L2-normalize rows (q then m) -> fp8, one wave per row ---
// R7: vectorized (G13). Loads: 3x float2 (8B/lane, 512B/wave-instr) instead
// of 6 scalar f32. Stores: 3x ushort (cvt_pk_fp8_f32 packs 2 fp8/instr,
// 128B/wave-instr) instead of 6 byte-stores. Halves VALU converts too.
__global__ __launch_bounds__(256) void nrm_kernel(const float* __restrict__ qe,
                                                  const float* __restrict__ me,
                                                  unsigned char* __restrict__ yq,
                                                  unsigned char* __restrict__ ym) {
  const int row = blockIdx.x * 4 + (threadIdx.x >> 6);
  const int lane = threadIdx.x & 63;
  const float* xr;
  unsigned char* yr;
  if (row < QN) {
    xr = qe + (size_t)row * DN;
    yr = yq + (size_t)row * DN;
  } else {
    xr = me + (size_t)(row - QN) * DN;
    yr = ym + (size_t)(row - QN) * DN;
  }
  float2 v[3];
  float ss = 0.f;
#pragma unroll
  for (int i = 0; i < 3; ++i) {
    v[i] = *(const float2*)&xr[lane * 2 + i * 128];
    ss += v[i].x * v[i].x + v[i].y * v[i].y;
  }
#pragma unroll
  for (int m = 1; m < 64; m <<= 1) ss += __shfl_xor(ss, m);
  const float scale = 1.0f / fmaxf(sqrtf(ss), 1e-8f);
  unsigned short* yw = (unsigned short*)yr;
#pragma unroll
  for (int i = 0; i < 3; ++i) {
    const int p = __builtin_amdgcn_cvt_pk_fp8_f32(v[i].x * scale,
                                                  v[i].y * scale, 0, false);
    yw[lane + i * 64] = (unsigned short)(p & 0xffff);
  }
}

// ------- Kernel B: MX-fp8 GEMM, 3-buffer single-barrier pipeline ----------
// R5 structure VERBATIM (best measured: 88.1 µs, MfmaUtil 50%). R4 (full reg
// dbuf) spilled; R6 (kc0 loop-carry + 2nd barrier) regressed — R5 is the
// local optimum of this schedule family. Counters: matrix 1660 + LDS 1600
// cyc per visit-pair ~= 3300 wall, pipes alternating (phase-locked blocks).
__global__ __launch_bounds__(256, 2) void gemm_max_kernel(
    const unsigned char* __restrict__ qn8, const unsigned char* __restrict__ mn8,
    float* __restrict__ pmax) {
  __shared__ unsigned char Bs[NBUF * BTILE_B];  // 72 KB (A staged here first)
  __shared__ float smax[2][128];

  const int tid = threadIdx.x;
  const int wave = tid >> 6, lane = tid & 63;
  const int wr = wave >> 1, wc = wave & 1;   // waves: 2x2 over 128q x 64m
  const int quad = lane >> 4, l16 = lane & 15;
  const int r7 = l16 & 7;

  // --- XCD-partitioned bijective swizzle (HW assigns XCD = linear id % 8) ---
  const int bid = blockIdx.y * gridDim.x + blockIdx.x;  // linear dispatch id
  const int xcd = bid & 7;
  const int j = bid >> 3;                    // 0..255 within this XCD
  const int ychunk = (xcd << 3) | (j >> 5);  // 8 m-chunks per XCD
  const int qrow0 = (j & 31) * 128;          // x sweeps fastest
  const int mchunk0 = ychunk * MROWS_PER_CHUNK;

  float rmax[16];
#pragma unroll
  for (int i = 0; i < 16; ++i) rmax[i] = -3.0e38f;

  // ---- stage A tile (128x384 = 48 KB) once, hoist fragments to registers --
  {
    const unsigned char* abase = qn8 + (size_t)qrow0 * DN;
#pragma unroll
    for (int i = 0; i < 12; ++i) {
      const int ci = i * 256 + tid;               // 16B chunk 0..3071
      const int row = ci / 24;
      const int jj = ci - row * 24;
      const int gj = (jj & 24) | ((jj ^ row) & 7);  // XOR-swizzled source chunk
      async16(abase + row * DN + gj * 16, &Bs[(i * 256 + wave * 64) * 16]);
    }
  }
  __syncthreads();  // full drain: A staged
  i32x8 afr[3][4];
#pragma unroll
  for (int kc = 0; kc < 3; ++kc)
#pragma unroll
    for (int rt = 0; rt < 4; ++rt) {
      const unsigned char* p = &Bs[(wr * 64 + rt * 16 + l16) * DN];
      i32x4 lo = *(const i32x4*)&p[(kc * 8 + ((quad * 2 + 0) ^ r7)) * 16];
      i32x4 hi = *(const i32x4*)&p[(kc * 8 + ((quad * 2 + 1) ^ r7)) * 16];
      afr[kc][rt][0] = lo[0]; afr[kc][rt][1] = lo[1];
      afr[kc][rt][2] = lo[2]; afr[kc][rt][3] = lo[3];
      afr[kc][rt][4] = hi[0]; afr[kc][rt][5] = hi[1];
      afr[kc][rt][6] = hi[2]; afr[kc][rt][7] = hi[3];
    }
  __syncthreads();  // afr reads done; LDS free for B staging

  // B staging source offsets: 6 issues/thread per 64-row tile (1536 chunks)
  int srcoff[6];
#pragma unroll
  for (int i = 0; i < 6; ++i) {
    const int ci = i * 256 + tid;                 // 16B chunk 0..1535
    const int row = ci / 24;
    const int jj = ci - row * 24;
    const int gj = (jj & 24) | ((jj ^ row) & 7);
    srcoff[i] = row * DN + gj * 16;
  }

  const unsigned char* bchunk = mn8 + (size_t)mchunk0 * DN;
  // depth-2 prologue: tile 0 -> buf 0, tile 1 -> buf 1 (12 loads in flight)
#pragma unroll
  for (int t = 0; t < 2; ++t)
#pragma unroll
    for (int i = 0; i < 6; ++i)
      async16(bchunk + (size_t)t * BTILE_B + srcoff[i],
              &Bs[t * BTILE_B + (i * 256 + wave * 64) * 16]);

  int cb = 0;                    // buffer holding tile mt
  int sb = 2;                    // buffer to stage tile mt+2 into

#pragma unroll 1
  for (int mt = 0; mt < MT_PER; ++mt) {
    // tile mt landed; keep tile mt+1's 6 loads in flight (tail: drain)
    if (mt + 1 < MT_PER)
      asm volatile("s_waitcnt vmcnt(6)" ::: "memory");
    else
      asm volatile("s_waitcnt vmcnt(0)" ::: "memory");
    __builtin_amdgcn_s_barrier();            // all waves: tile mt visible,
                                             // tile mt-1 reads complete
    __builtin_amdgcn_sched_barrier(0);       // keep reads below the barrier

    const unsigned char* cur = &Bs[cb * BTILE_B];

    // 12 B-fragment ds_reads — NO manual lgkm pin; compiler interleaves
    // partial lgkmcnt waits with the MFMA cluster below.
    i32x8 bfr[3][2];
#pragma unroll
    for (int kc = 0; kc < 3; ++kc)
#pragma unroll
      for (int ct = 0; ct < 2; ++ct) {
        const unsigned char* p = &cur[(wc * 32 + ct * 16 + l16) * DN];
        i32x4 lo = *(const i32x4*)&p[(kc * 8 + ((quad * 2 + 0) ^ r7)) * 16];
        i32x4 hi = *(const i32x4*)&p[(kc * 8 + ((quad * 2 + 1) ^ r7)) * 16];
        bfr[kc][ct][0] = lo[0]; bfr[kc][ct][1] = lo[1];
        bfr[kc][ct][2] = lo[2]; bfr[kc][ct][3] = lo[3];
        bfr[kc][ct][4] = hi[0]; bfr[kc][ct][5] = hi[1];
        bfr[kc][ct][6] = hi[2]; bfr[kc][ct][7] = hi[3];
      }

    // stage tile mt+2 into buf sb (last read in iter mt-1; safe past barrier)
    if (mt + 2 < MT_PER) {
      unsigned char* dst = &Bs[sb * BTILE_B];
      const unsigned char* nb = bchunk + (size_t)(mt + 2) * BTILE_B;
#pragma unroll
      for (int i = 0; i < 6; ++i)
        async16(nb + srcoff[i], &dst[(i * 256 + wave * 64) * 16]);
    }

    f32x4 acc[4][2];
#pragma unroll
    for (int rt = 0; rt < 4; ++rt)
#pragma unroll
      for (int ct = 0; ct < 2; ++ct) acc[rt][ct] = (f32x4){0.f, 0.f, 0.f, 0.f};

    __builtin_amdgcn_s_setprio(1);
#pragma unroll
    for (int kc = 0; kc < 3; ++kc)
#pragma unroll
      for (int rt = 0; rt < 4; ++rt)
#pragma unroll
        for (int ct = 0; ct < 2; ++ct)
          acc[rt][ct] = __builtin_amdgcn_mfma_scale_f32_16x16x128_f8f6f4(
              afr[kc][rt], bfr[kc][ct], acc[rt][ct], 0, 0,  // fmt fp8/fp8
              0, 0x7f7f7f7f, 0, 0x7f7f7f7f);                // scales = 1.0
    __builtin_amdgcn_s_setprio(0);

#pragma unroll
    for (int rt = 0; rt < 4; ++rt)
#pragma unroll
      for (int r = 0; r < 4; ++r) {
        const float v = fmaxf(acc[rt][0][r], acc[rt][1][r]);
        rmax[rt * 4 + r] = fmaxf(rmax[rt * 4 + r], v);
      }

    // rotate buffers: cb -> cb+1, sb -> sb+1 (mod 3)
    cb = (cb == 2) ? 0 : cb + 1;
    sb = (sb == 2) ? 0 : sb + 1;
  }

#pragma unroll
  for (int i = 0; i < 16; ++i) {
    float v = rmax[i];
    v = fmaxf(v, __shfl_xor(v, 1));
    v = fmaxf(v, __shfl_xor(v, 2));
    v = fmaxf(v, __shfl_xor(v, 4));
    v = fmaxf(v, __shfl_xor(v, 8));
    rmax[i] = v;
  }
  if (l16 == 0) {
#pragma unroll
    for (int rt = 0; rt < 4; ++rt)
#pragma unroll
      for (int r = 0; r < 4; ++r)
        smax[wc][wr * 64 + rt * 16 + quad * 4 + r] = rmax[rt * 4 + r];
  }
  __syncthreads();
  if (tid < 128) {
    const float v = fmaxf(smax[0][tid], smax[1][tid]);
    pmax[(size_t)(qrow0 + tid) * NCHUNK + ychunk] = v;
  }
}

// ------- Kernel C: reduce partials; uniform row OR exact fp32 re-check -----
__global__ __launch_bounds__(256) void decide_kernel(
    const float* __restrict__ pmax, const float* __restrict__ qe,
    const float* __restrict__ me, const float* __restrict__ labels,
    float* __restrict__ out) {
  const int q = blockIdx.x;
  const int t = threadIdx.x;  // 256
  __shared__ float smx;
  if (t < 64) {
    float v = pmax[(size_t)q * NCHUNK + t];  // NCHUNK == 64
#pragma unroll
    for (int m = 1; m < 64; m <<= 1) v = fmaxf(v, __shfl_xor(v, m));
    if (t == 0) smx = v;
  }
  __syncthreads();
  if (smx <= 0.5f) {  // uniform fast path (expected for all queries)
    if (t < CN) out[(size_t)q * CN + t] = 1.0f / 128.0f;
    return;
  }
  // exact fp32 path (rare / borderline queries only)
  __shared__ float sred[256];
  __shared__ int sidx[256];
  __shared__ float wsum[4];
  const float* qr = qe + (size_t)q * DN;
  float ss = 0.f;
  for (int i = t; i < DN; i += 256) ss += qr[i] * qr[i];
#pragma unroll
  for (int m = 1; m < 64; m <<= 1) ss += __shfl_xor(ss, m);
  if ((t & 63) == 0) wsum[t >> 6] = ss;
  __syncthreads();
  const float qnorm = fmaxf(sqrtf(wsum[0] + wsum[1] + wsum[2] + wsum[3]), 1e-8f);

  float best = -3.0e38f;
  int bidx = 0x7fffffff;
  for (int j = t; j < MN; j += 256) {
    const float* mr = me + (size_t)j * DN;
    float dot = 0.f, ms = 0.f;
    for (int k = 0; k < DN; ++k) {
      float a = qr[k], b = mr[k];
      dot += a * b;
      ms += b * b;
    }
    const float sim = dot / (qnorm * fmaxf(sqrtf(ms), 1e-8f));
    if (sim > best) { best = sim; bidx = j; }  // strict > keeps first index
  }
  sred[t] = best;
  sidx[t] = bidx;
  __syncthreads();
  for (int s = 128; s > 0; s >>= 1) {
    if (t < s) {
      const float ov = sred[t + s];
      const int oi = sidx[t + s];
      if (ov > sred[t] || (ov == sred[t] && oi < sidx[t])) {
        sred[t] = ov;
        sidx[t] = oi;
      }
    }
    __syncthreads();
  }
  const float mx = sred[0];
  const int mi = sidx[0];
  if (t < CN)
    out[(size_t)q * CN + t] =
        (mx > 0.7f) ? labels[(size_t)mi * CN + t] : (1.0f / 128.0f);
}

extern "C" void kernel_launch(void* const* d_in, const int* in_sizes, int n_in,
                              void* d_out, int out_size, void* d_ws,
                              size_t ws_size, hipStream_t stream) {
  const float* qe = (const float*)d_in[0];  // [4096,384] f32
  const float* me = (const float*)d_in[1];  // [65536,384] f32
  const float* lb = (const float*)d_in[2];  // [65536,128] f32
  float* out = (float*)d_out;               // [4096,128] f32

  char* ws = (char*)d_ws;
  const size_t OFF_QN = 0;
  const size_t OFF_MN = OFF_QN + (size_t)QN * DN;        // 1,572,864
  const size_t OFF_PMAX = OFF_MN + (size_t)MN * DN;      // +25,165,824
  unsigned char* qn8 = (unsigned char*)(ws + OFF_QN);
  unsigned char* mn8 = (unsigned char*)(ws + OFF_MN);
  float* pmax = (float*)(ws + OFF_PMAX);                 // [4096][64] = 1 MB

  nrm_kernel<<<(QN + MN) / 4, 256, 0, stream>>>(qe, me, qn8, mn8);
  gemm_max_kernel<<<dim3(QN / 128, NCHUNK), 256, 0, stream>>>(qn8, mn8, pmax);
  decide_kernel<<<QN, 256, 0, stream>>>(pmax, qe, me, lb, out);
}

// Round 8
// 245.529 us; speedup vs baseline: 1.0392x; 1.0042x over previous
//
#include <hip/hip_runtime.h>
#include <math.h>

// Problem constants
#define QN 4096
#define MN 65536
#define DN 384
#define CN 128
#define NCHUNK 64                 // m-chunks
#define MROWS_PER_CHUNK (MN / NCHUNK)   // 1024
#define MT_PER (MROWS_PER_CHUNK / 64)   // 16 m-tiles (64 rows) per block
#define BTILE_B (64 * DN)               // 24576 B per B tile
#define NBUF 2                          // R8: 2 buffers -> 50,176 B LDS
                                        // -> 3 blocks/CU (was 2 at 74,752 B)

typedef __attribute__((ext_vector_type(8))) int i32x8;
typedef __attribute__((ext_vector_type(4))) int i32x4;
typedef __attribute__((ext_vector_type(4))) float f32x4;

__device__ __forceinline__ void async16(const void* g, void* l) {
  __builtin_amdgcn_global_load_lds(
      (const __attribute__((address_space(1))) unsigned int*)g,
      (__attribute__((address_space(3))) unsigned int*)l, 16, 0, 0);
}

// ------- Kernel A: L2-normalize rows (q then m) -> fp8, one wave per row ---
// Vectorized (G13): float2 loads, cvt_pk_fp8 paired ushort stores.
__global__ __launch_bounds__(256) void nrm_kernel(const float* __restrict__ qe,
                                                  const float* __restrict__ me,
                                                  unsigned char* __restrict__ yq,
                                                  unsigned char* __restrict__ ym) {
  const int row = blockIdx.x * 4 + (threadIdx.x >> 6);
  const int lane = threadIdx.x & 63;
  const float* xr;
  unsigned char* yr;
  if (row < QN) {
    xr = qe + (size_t)row * DN;
    yr = yq + (size_t)row * DN;
  } else {
    xr = me + (size_t)(row - QN) * DN;
    yr = ym + (size_t)(row - QN) * DN;
  }
  float2 v[3];
  float ss = 0.f;
#pragma unroll
  for (int i = 0; i < 3; ++i) {
    v[i] = *(const float2*)&xr[lane * 2 + i * 128];
    ss += v[i].x * v[i].x + v[i].y * v[i].y;
  }
#pragma unroll
  for (int m = 1; m < 64; m <<= 1) ss += __shfl_xor(ss, m);
  const float scale = 1.0f / fmaxf(sqrtf(ss), 1e-8f);
  unsigned short* yw = (unsigned short*)yr;
#pragma unroll
  for (int i = 0; i < 3; ++i) {
    const int p = __builtin_amdgcn_cvt_pk_fp8_f32(v[i].x * scale,
                                                  v[i].y * scale, 0, false);
    yw[lane + i * 64] = (unsigned short)(p & 0xffff);
  }
}

// ------- Kernel B: MX-fp8 GEMM, 2-buffer / 3-blocks-per-CU pipeline --------
// R8: R5's single-barrier schedule with NBUF 3->2. Motivation (R7 decode):
//  * SQ_LDS_BANK_CONFLICT == 8 x gload_lds instr count exactly — structural
//    write-beat counting, NOT read conflicts. No layout work left.
//  * Per CU: MFMA pipe 106k cyc (44 µs floor), LDS pipe ~75k, wall 222k —
//    two barrier-locked blocks alternate phases, both pipes ~50% idle.
//  * 50,176 B LDS -> 3 blocks/CU: three independent barrier rhythms break
//    the lockstep; matrix-pipe feed 1.5x.
// Depth-1 prefetch + vmcnt(0) at top is sufficient: B is L2-resident (R1),
// load latency 200-400 cyc << the ~900 cyc MFMA phase it hides under.
// 2-buffer safety: a wave's reads of tile t-1 are consumed by its MFMAs
// (lgkm waits) before it re-arrives at the top barrier of iter t; staging
// of t+1 into buf (t+1)&1 (last read in iter t-1) issues only after that
// barrier -> no WAR hazard.
__global__ __launch_bounds__(256, 2) void gemm_max_kernel(
    const unsigned char* __restrict__ qn8, const unsigned char* __restrict__ mn8,
    float* __restrict__ pmax) {
  __shared__ unsigned char Bs[NBUF * BTILE_B];  // 48 KB (A staged here first)
  __shared__ float smax[2][128];

  const int tid = threadIdx.x;
  const int wave = tid >> 6, lane = tid & 63;
  const int wr = wave >> 1, wc = wave & 1;   // waves: 2x2 over 128q x 64m
  const int quad = lane >> 4, l16 = lane & 15;
  const int r7 = l16 & 7;

  // --- XCD-partitioned bijective swizzle (HW assigns XCD = linear id % 8) ---
  const int bid = blockIdx.y * gridDim.x + blockIdx.x;  // linear dispatch id
  const int xcd = bid & 7;
  const int j = bid >> 3;                    // 0..255 within this XCD
  const int ychunk = (xcd << 3) | (j >> 5);  // 8 m-chunks per XCD
  const int qrow0 = (j & 31) * 128;          // x sweeps fastest
  const int mchunk0 = ychunk * MROWS_PER_CHUNK;

  float rmax[16];
#pragma unroll
  for (int i = 0; i < 16; ++i) rmax[i] = -3.0e38f;

  // ---- stage A tile (128x384 = 48 KB) once, hoist fragments to registers --
  {
    const unsigned char* abase = qn8 + (size_t)qrow0 * DN;
#pragma unroll
    for (int i = 0; i < 12; ++i) {
      const int ci = i * 256 + tid;               // 16B chunk 0..3071
      const int row = ci / 24;
      const int jj = ci - row * 24;
      const int gj = (jj & 24) | ((jj ^ row) & 7);  // XOR-swizzled source chunk
      async16(abase + row * DN + gj * 16, &Bs[(i * 256 + wave * 64) * 16]);
    }
  }
  __syncthreads();  // full drain: A staged
  i32x8 afr[3][4];
#pragma unroll
  for (int kc = 0; kc < 3; ++kc)
#pragma unroll
    for (int rt = 0; rt < 4; ++rt) {
      const unsigned char* p = &Bs[(wr * 64 + rt * 16 + l16) * DN];
      i32x4 lo = *(const i32x4*)&p[(kc * 8 + ((quad * 2 + 0) ^ r7)) * 16];
      i32x4 hi = *(const i32x4*)&p[(kc * 8 + ((quad * 2 + 1) ^ r7)) * 16];
      afr[kc][rt][0] = lo[0]; afr[kc][rt][1] = lo[1];
      afr[kc][rt][2] = lo[2]; afr[kc][rt][3] = lo[3];
      afr[kc][rt][4] = hi[0]; afr[kc][rt][5] = hi[1];
      afr[kc][rt][6] = hi[2]; afr[kc][rt][7] = hi[3];
    }
  __syncthreads();  // afr reads done; LDS free for B staging

  // B staging source offsets: 6 issues/thread per 64-row tile (1536 chunks)
  int srcoff[6];
#pragma unroll
  for (int i = 0; i < 6; ++i) {
    const int ci = i * 256 + tid;                 // 16B chunk 0..1535
    const int row = ci / 24;
    const int jj = ci - row * 24;
    const int gj = (jj & 24) | ((jj ^ row) & 7);
    srcoff[i] = row * DN + gj * 16;
  }

  const unsigned char* bchunk = mn8 + (size_t)mchunk0 * DN;
  // depth-1 prologue: tile 0 -> buf 0 (6 loads in flight)
#pragma unroll
  for (int i = 0; i < 6; ++i)
    async16(bchunk + srcoff[i], &Bs[(i * 256 + wave * 64) * 16]);

#pragma unroll 1
  for (int mt = 0; mt < MT_PER; ++mt) {
    // all outstanding loads are tile mt's 6 (issued last iter / prologue)
    asm volatile("s_waitcnt vmcnt(0)" ::: "memory");
    __builtin_amdgcn_s_barrier();            // all waves: tile mt visible,
                                             // tile mt-1 reads complete
    __builtin_amdgcn_sched_barrier(0);       // keep reads below the barrier

    const unsigned char* cur = &Bs[(mt & 1) * BTILE_B];

    // 12 B-fragment ds_reads — NO manual lgkm pin; compiler interleaves
    // partial lgkmcnt waits with the MFMA cluster below.
    i32x8 bfr[3][2];
#pragma unroll
    for (int kc = 0; kc < 3; ++kc)
#pragma unroll
      for (int ct = 0; ct < 2; ++ct) {
        const unsigned char* p = &cur[(wc * 32 + ct * 16 + l16) * DN];
        i32x4 lo = *(const i32x4*)&p[(kc * 8 + ((quad * 2 + 0) ^ r7)) * 16];
        i32x4 hi = *(const i32x4*)&p[(kc * 8 + ((quad * 2 + 1) ^ r7)) * 16];
        bfr[kc][ct][0] = lo[0]; bfr[kc][ct][1] = lo[1];
        bfr[kc][ct][2] = lo[2]; bfr[kc][ct][3] = lo[3];
        bfr[kc][ct][4] = hi[0]; bfr[kc][ct][5] = hi[1];
        bfr[kc][ct][6] = hi[2]; bfr[kc][ct][7] = hi[3];
      }

    // stage tile mt+1 into buf (mt+1)&1 (safe: last read in iter mt-1,
    // all waves past the top barrier of this iter)
    if (mt + 1 < MT_PER) {
      unsigned char* dst = &Bs[((mt + 1) & 1) * BTILE_B];
      const unsigned char* nb = bchunk + (size_t)(mt + 1) * BTILE_B;
#pragma unroll
      for (int i = 0; i < 6; ++i)
        async16(nb + srcoff[i], &dst[(i * 256 + wave * 64) * 16]);
    }

    f32x4 acc[4][2];
#pragma unroll
    for (int rt = 0; rt < 4; ++rt)
#pragma unroll
      for (int ct = 0; ct < 2; ++ct) acc[rt][ct] = (f32x4){0.f, 0.f, 0.f, 0.f};

    __builtin_amdgcn_s_setprio(1);
#pragma unroll
    for (int kc = 0; kc < 3; ++kc)
#pragma unroll
      for (int rt = 0; rt < 4; ++rt)
#pragma unroll
        for (int ct = 0; ct < 2; ++ct)
          acc[rt][ct] = __builtin_amdgcn_mfma_scale_f32_16x16x128_f8f6f4(
              afr[kc][rt], bfr[kc][ct], acc[rt][ct], 0, 0,  // fmt fp8/fp8
              0, 0x7f7f7f7f, 0, 0x7f7f7f7f);                // scales = 1.0
    __builtin_amdgcn_s_setprio(0);

#pragma unroll
    for (int rt = 0; rt < 4; ++rt)
#pragma unroll
      for (int r = 0; r < 4; ++r) {
        const float v = fmaxf(acc[rt][0][r], acc[rt][1][r]);
        rmax[rt * 4 + r] = fmaxf(rmax[rt * 4 + r], v);
      }
  }

#pragma unroll
  for (int i = 0; i < 16; ++i) {
    float v = rmax[i];
    v = fmaxf(v, __shfl_xor(v, 1));
    v = fmaxf(v, __shfl_xor(v, 2));
    v = fmaxf(v, __shfl_xor(v, 4));
    v = fmaxf(v, __shfl_xor(v, 8));
    rmax[i] = v;
  }
  if (l16 == 0) {
#pragma unroll
    for (int rt = 0; rt < 4; ++rt)
#pragma unroll
      for (int r = 0; r < 4; ++r)
        smax[wc][wr * 64 + rt * 16 + quad * 4 + r] = rmax[rt * 4 + r];
  }
  __syncthreads();
  if (tid < 128) {
    const float v = fmaxf(smax[0][tid], smax[1][tid]);
    pmax[(size_t)(qrow0 + tid) * NCHUNK + ychunk] = v;
  }
}

// ------- Kernel C: reduce partials; uniform row OR exact fp32 re-check -----
__global__ __launch_bounds__(256) void decide_kernel(
    const float* __restrict__ pmax, const float* __restrict__ qe,
    const float* __restrict__ me, const float* __restrict__ labels,
    float* __restrict__ out) {
  const int q = blockIdx.x;
  const int t = threadIdx.x;  // 256
  __shared__ float smx;
  if (t < 64) {
    float v = pmax[(size_t)q * NCHUNK + t];  // NCHUNK == 64
#pragma unroll
    for (int m = 1; m < 64; m <<= 1) v = fmaxf(v, __shfl_xor(v, m));
    if (t == 0) smx = v;
  }
  __syncthreads();
  if (smx <= 0.5f) {  // uniform fast path (expected for all queries)
    if (t < CN) out[(size_t)q * CN + t] = 1.0f / 128.0f;
    return;
  }
  // exact fp32 path (rare / borderline queries only)
  __shared__ float sred[256];
  __shared__ int sidx[256];
  __shared__ float wsum[4];
  const float* qr = qe + (size_t)q * DN;
  float ss = 0.f;
  for (int i = t; i < DN; i += 256) ss += qr[i] * qr[i];
#pragma unroll
  for (int m = 1; m < 64; m <<= 1) ss += __shfl_xor(ss, m);
  if ((t & 63) == 0) wsum[t >> 6] = ss;
  __syncthreads();
  const float qnorm = fmaxf(sqrtf(wsum[0] + wsum[1] + wsum[2] + wsum[3]), 1e-8f);

  float best = -3.0e38f;
  int bidx = 0x7fffffff;
  for (int j = t; j < MN; j += 256) {
    const float* mr = me + (size_t)j * DN;
    float dot = 0.f, ms = 0.f;
    for (int k = 0; k < DN; ++k) {
      float a = qr[k], b = mr[k];
      dot += a * b;
      ms += b * b;
    }
    const float sim = dot / (qnorm * fmaxf(sqrtf(ms), 1e-8f));
    if (sim > best) { best = sim; bidx = j; }  // strict > keeps first index
  }
  sred[t] = best;
  sidx[t] = bidx;
  __syncthreads();
  for (int s = 128; s > 0; s >>= 1) {
    if (t < s) {
      const float ov = sred[t + s];
      const int oi = sidx[t + s];
      if (ov > sred[t] || (ov == sred[t] && oi < sidx[t])) {
        sred[t] = ov;
        sidx[t] = oi;
      }
    }
    __syncthreads();
  }
  const float mx = sred[0];
  const int mi = sidx[0];
  if (t < CN)
    out[(size_t)q * CN + t] =
        (mx > 0.7f) ? labels[(size_t)mi * CN + t] : (1.0f / 128.0f);
}

extern "C" void kernel_launch(void* const* d_in, const int* in_sizes, int n_in,
                              void* d_out, int out_size, void* d_ws,
                              size_t ws_size, hipStream_t stream) {
  const float* qe = (const float*)d_in[0];  // [4096,384] f32
  const float* me = (const float*)d_in[1];  // [65536,384] f32
  const float* lb = (const float*)d_in[2];  // [65536,128] f32
  float* out = (float*)d_out;               // [4096,128] f32

  char* ws = (char*)d_ws;
  const size_t OFF_QN = 0;
  const size_t OFF_MN = OFF_QN + (size_t)QN * DN;        // 1,572,864
  const size_t OFF_PMAX = OFF_MN + (size_t)MN * DN;      // +25,165,824
  unsigned char* qn8 = (unsigned char*)(ws + OFF_QN);
  unsigned char* mn8 = (unsigned char*)(ws + OFF_MN);
  float* pmax = (float*)(ws + OFF_PMAX);                 // [4096][64] = 1 MB

  nrm_kernel<<<(QN + MN) / 4, 256, 0, stream>>>(qe, me, qn8, mn8);
  gemm_max_kernel<<<dim3(QN / 128, NCHUNK), 256, 0, stream>>>(qn8, mn8, pmax);
  decide_kernel<<<QN, 256, 0, stream>>>(pmax, qe, me, lb, out);
}